// Round 21
// baseline (145.026 us; speedup 1.0000x reference)
//
#include <hip/hip_runtime.h>
#include <cstdint>
#include <cstddef>

// ---------------------------------------------------------------------------
// AttnBlock, 4 dispatches, every GEMM grid = exactly one resident round:
//   prep(1024thr): W2=wp.wv + bpv + rowsum=0; WqkT=rsK*wk^T.wq + cu;
//                  GN single-pass (4 chans/thread, 32 waves/CU) -> hT
//   tmp|vP: gemm512 (256+256 blocks)   tmp = hT.WqkT^T + cu ; vP = W2.hT + bpv
//   scores: gemm512 (512 blocks)       E = exp(tmp.hT^T) + atomic rowsum
//   PV':    gemm128  (512 blocks)      out = x + bp + vP.E^T / rowsum
// gemm512 = BM256xBN128, 512 thr = 8 waves (4m x 2n), per-wave 64x64,
// 48KB LDS -> 2 blocks/CU = 16 waves/CU (R20: +14us vs 4-wave engine).
// Algebra: qk eliminated via softmax shift-invariance (WqkT = rsK*wk^T.wq,
// j-only cu = rsK*wk^T.bq); v/proj folded into W2 = wp.wv.
// Pinned: BM256 4-wave (256,3) spills (R10); grids = 1 round (R12);
// wave-uniform K-loop reads -> LDS-stage (R13); 8-phase loses at K=512 (R16);
// flash fusion blocked at head-dim 512.
// ---------------------------------------------------------------------------

typedef __bf16 bf16x8 __attribute__((ext_vector_type(8)));
typedef float f32x4 __attribute__((ext_vector_type(4)));

typedef __attribute__((address_space(1))) const void gl_void;
typedef __attribute__((address_space(3))) void lds_void;

#define GLD16(g, l)                                                     \
  __builtin_amdgcn_global_load_lds((gl_void*)(uintptr_t)(g),            \
                                   (lds_void*)(uintptr_t)(l), 16, 0, 0)

__device__ __forceinline__ unsigned short f2bf(float f) {
  unsigned int u = __builtin_bit_cast(unsigned int, f);
  u += 0x7fffu + ((u >> 16) & 1u);  // round-to-nearest-even
  return (unsigned short)(u >> 16);
}
__device__ __forceinline__ float bf2f(unsigned int h) {
  return __builtin_bit_cast(float, h << 16);
}

// ---- prep (1024 thr): W2 (0-127) + WqkT/cu (128-255) + GN (256-767) -------
// W2/Wqk branches: proven 512-thread bodies under t<512 guards; barriers at
// block level (waves 8-15 idle through).
__global__ __launch_bounds__(1024) void prep_kernel(
    const float* __restrict__ x, const float* __restrict__ gsc,
    const float* __restrict__ gbi, unsigned short* __restrict__ hT,
    const float* __restrict__ wq, const float* __restrict__ wk,
    const float* __restrict__ wv, const float* __restrict__ wp,
    const float* __restrict__ bq, const float* __restrict__ bv,
    unsigned short* __restrict__ WqkTo, unsigned short* __restrict__ W2o,
    float* __restrict__ cu, float* __restrict__ bpv,
    float* __restrict__ rowsum, float rsK) {
  const int t = threadIdx.x;
  const int wid = t >> 6, lane = t & 63;
  if (blockIdx.x < 128) {  // ---- W2 = wp.wv (fp32), bpv = wp.bv, rowsum=0 ----
    __shared__ float swp[4][512];
    __shared__ float sbv[512];
    __shared__ float redp[4][8];
    const int o0 = blockIdx.x * 4;
    if (t < 512) {
#pragma unroll
      for (int r = 0; r < 4; ++r)
        swp[r][t] = wp[(size_t)(o0 + r) * 512 + t];
      sbv[t] = bv[t];
      if (t < 128) rowsum[blockIdx.x * 128 + t] = 0.f;
    }
    __syncthreads();
    if (t < 512) {
      float a0[4] = {};
      for (int c = 0; c < 512; ++c) {
        const float v0 = wv[(size_t)c * 512 + t];
#pragma unroll
        for (int r = 0; r < 4; ++r) a0[r] = fmaf(swp[r][c], v0, a0[r]);
      }
#pragma unroll
      for (int r = 0; r < 4; ++r)
        W2o[(size_t)(o0 + r) * 512 + t] = f2bf(a0[r]);
      float s[4];
#pragma unroll
      for (int r = 0; r < 4; ++r) s[r] = swp[r][t] * sbv[t];
#pragma unroll
      for (int r = 0; r < 4; ++r)
#pragma unroll
        for (int off = 32; off > 0; off >>= 1) s[r] += __shfl_down(s[r], off);
      if (lane == 0) {
#pragma unroll
        for (int r = 0; r < 4; ++r) redp[r][wid] = s[r];
      }
    }
    __syncthreads();
    if (t == 0) {
#pragma unroll
      for (int r = 0; r < 4; ++r) {
        float acc = 0.f;
#pragma unroll
        for (int w = 0; w < 8; ++w) acc += redp[r][w];
        bpv[o0 + r] = acc;
      }
    }
    return;
  }
  if (blockIdx.x < 256) {  // ---- WqkT[n][c] = rsK*sum_o wk[o][n] wq[o][c] ----
    __shared__ float swk[512][4];
    __shared__ float sbq[512];
    __shared__ float redq[4][8];
    const int n0 = (blockIdx.x - 128) * 4;
    if (t < 512) {
      *(float4*)&swk[t][0] = *(const float4*)&wk[(size_t)t * 512 + n0];
      sbq[t] = bq[t];
    }
    __syncthreads();
    if (t < 512) {
      float a0[4] = {};
      for (int o = 0; o < 512; ++o) {
        const float q0 = wq[(size_t)o * 512 + t];
#pragma unroll
        for (int r = 0; r < 4; ++r) a0[r] = fmaf(swk[o][r], q0, a0[r]);
      }
#pragma unroll
      for (int r = 0; r < 4; ++r)
        WqkTo[(size_t)(n0 + r) * 512 + t] = f2bf(a0[r] * rsK);
      float s[4];
#pragma unroll
      for (int r = 0; r < 4; ++r) s[r] = swk[t][r] * sbq[t];
#pragma unroll
      for (int r = 0; r < 4; ++r)
#pragma unroll
        for (int off = 32; off > 0; off >>= 1) s[r] += __shfl_down(s[r], off);
      if (lane == 0) {
#pragma unroll
        for (int r = 0; r < 4; ++r) redq[r][wid] = s[r];
      }
    }
    __syncthreads();
    if (t == 0) {
#pragma unroll
      for (int r = 0; r < 4; ++r) {
        float acc = 0.f;
#pragma unroll
        for (int w = 0; w < 8; ++w) acc += redq[r][w];
        cu[n0 + r] = rsK * acc;
      }
    }
    return;
  }
  // ---- GroupNorm, single pass: thread (col, cq) owns 4 chans ----
  __shared__ float red[2][16];
  const int gb = blockIdx.x - 256;
  const int b = gb >> 5;
  const int g = gb & 31;
  const int col = t & 255;   // float4 column (rows 4col..4col+3)
  const int cq = t >> 8;     // channel quarter: chans cq*4..cq*4+3
  const float* xp = x + ((size_t)(b * 512 + g * 16 + cq * 4)) * 1024;

  float4 r4[4];  // this thread's 4 channels stay live (16 VGPR)
  float s = 0.f, s2 = 0.f;
#pragma unroll
  for (int c = 0; c < 4; ++c) {
    r4[c] = ((const float4*)(xp + (size_t)c * 1024))[col];
    s += (r4[c].x + r4[c].y) + (r4[c].z + r4[c].w);
    s2 += (r4[c].x * r4[c].x + r4[c].y * r4[c].y) +
          (r4[c].z * r4[c].z + r4[c].w * r4[c].w);
  }
#pragma unroll
  for (int off = 32; off > 0; off >>= 1) {
    s += __shfl_down(s, off);
    s2 += __shfl_down(s2, off);
  }
  if (lane == 0) { red[0][wid] = s; red[1][wid] = s2; }
  __syncthreads();
  float S = 0.f, S2 = 0.f;
#pragma unroll
  for (int w = 0; w < 16; ++w) { S += red[0][w]; S2 += red[1][w]; }
  const float mean = S * (1.f / 16384.f);
  const float var = S2 * (1.f / 16384.f) - mean * mean;
  const float rstd = rsqrtf(var + 1e-6f);

  float sc[4], bi[4];
#pragma unroll
  for (int c = 0; c < 4; ++c) {
    sc[c] = gsc[g * 16 + cq * 4 + c] * rstd;
    bi[c] = gbi[g * 16 + cq * 4 + c] - mean * sc[c];
  }
  unsigned short* hp = hT + (size_t)b * 1024 * 512 + g * 16 + cq * 4;
#pragma unroll
  for (int ii = 0; ii < 4; ++ii) {  // float4 component = row 4col+ii
    const int i = 4 * col + ii;
    float e0, e1, e2, e3;
    if (ii == 0) { e0 = r4[0].x; e1 = r4[1].x; e2 = r4[2].x; e3 = r4[3].x; }
    else if (ii == 1) { e0 = r4[0].y; e1 = r4[1].y; e2 = r4[2].y; e3 = r4[3].y; }
    else if (ii == 2) { e0 = r4[0].z; e1 = r4[1].z; e2 = r4[2].z; e3 = r4[3].z; }
    else { e0 = r4[0].w; e1 = r4[1].w; e2 = r4[2].w; e3 = r4[3].w; }
    uint2 pk;
    pk.x = (unsigned int)f2bf(e0 * sc[0] + bi[0]) |
           ((unsigned int)f2bf(e1 * sc[1] + bi[1]) << 16);
    pk.y = (unsigned int)f2bf(e2 * sc[2] + bi[2]) |
           ((unsigned int)f2bf(e3 * sc[3] + bi[3]) << 16);
    *(uint2*)(hp + (size_t)i * 512) = pk;
  }
}

// ------------------------- GEMM argument block -----------------------------
struct GArgs {
  const unsigned short *A, *B;
  void* Out;
  const float *bias, *resid;
  float* rowsum;
  long long sBb, sOb;
  int lda, ldb, ldo, btshift, obf, csplit, K, bmode, nx, nwg, epi;
  float scale;
};

// Shared epilogue (per-wave 64x64 tile, MF=4), used by both engines.
__device__ __forceinline__ void epilogue4(
    const GArgs& g, f32x4 acc[4][4], int em, int en, int lane) {
  float rdiv[4];
  if (g.epi == 4) {
    const int rbase = ((em >> 9) << 10);  // batch = row>>9
#pragma unroll
    for (int nf = 0; nf < 4; ++nf)
      rdiv[nf] = 1.f / g.rowsum[rbase + en + nf * 16];
  }
#pragma unroll
  for (int mf = 0; mf < 4; ++mf) {
#pragma unroll
    for (int r = 0; r < 4; ++r) {
      const int gm = em + mf * 16 + r;
      if (g.epi == 2) {  // scores: exp, atomic row sum of ROUNDED values
        float rsum = 0.f;
#pragma unroll
        for (int nf = 0; nf < 4; ++nf) {
          const int gn = en + nf * 16;
          unsigned short h = f2bf(__expf(acc[mf][nf][r] * g.scale));
          rsum += bf2f(h);
          ((unsigned short*)g.Out)[(size_t)gm * g.ldo + gn] = h;
        }
        rsum += __shfl_xor(rsum, 1);
        rsum += __shfl_xor(rsum, 2);
        rsum += __shfl_xor(rsum, 4);
        rsum += __shfl_xor(rsum, 8);
        if ((lane & 15) == 0) atomicAdd(&g.rowsum[gm], rsum);
        continue;
      }
      if (g.epi == 4) {  // PV': normalize + bias + resid, fp32 row-major
        const float bb = g.bias[gm & 511];
#pragma unroll
        for (int nf = 0; nf < 4; ++nf) {
          const int gn = en + nf * 16;
          const size_t off = (size_t)gm * g.ldo + gn;
          ((float*)g.Out)[off] = acc[mf][nf][r] * rdiv[nf] + bb + g.resid[off];
        }
        continue;
      }
#pragma unroll
      for (int nf = 0; nf < 4; ++nf) {
        const int gn = en + nf * 16;
        float v = acc[mf][nf][r] * g.scale;
        if (g.bmode == 1) v += g.bias[gm];
        else if (g.bmode == 2) v += g.bias[gn];
        size_t off;
        if (g.csplit)
          off = (size_t)(gn >> 10) * g.sOb + (size_t)gm * g.ldo + (gn & 1023);
        else
          off = (size_t)gm * g.ldo + gn;
        if (g.resid) v += g.resid[off];
        if (g.obf) ((unsigned short*)g.Out)[off] = f2bf(v);
        else ((float*)g.Out)[off] = v;
      }
    }
  }
}

// -------- gemm512: BM256 x BN128, 512 thr = 8 waves (4m x 2n) --------------
__global__ __launch_bounds__(512) void gemm512(GArgs g0, GArgs g1, int split) {
  __shared__ char lds[49152];  // A 32KB @0, B 16KB @32768

  const bool r1 = (int)blockIdx.x >= split;
  const GArgs g = r1 ? g1 : g0;
  const int lid = blockIdx.x - (r1 ? split : 0);

  const int cpx = g.nwg >> 3;
  const int rid = (lid & 7) * cpx + (lid >> 3);
  const int bx = rid % g.nx, by = rid / g.nx;
  const int m0 = by * 256, n0 = bx * 128;

  const int t = threadIdx.x;  // 0..511
  const int wid = t >> 6, lane = t & 63;
  const int srow = t >> 3;
  const int schunk = ((t & 7) ^ (srow & 7)) * 8;
  const unsigned short* gA = g.A + (size_t)(m0 + srow) * g.lda + schunk;
  const unsigned short* gB =
      g.B + (g.btshift ? (size_t)(m0 >> g.btshift) * g.sBb : 0) +
      (size_t)(n0 + srow) * g.ldb + schunk;
  const int stgO = wid << 10;

  f32x4 acc[4][4] = {};
  const int wm = wid >> 1, wn = wid & 1;
  const int fr = lane & 15;
  const int slot0 = (((lane >> 4) ^ (fr & 7)) << 4);
  const int aoff = (wm * 64 + fr) * 128 + slot0;
  const int boff = 32768 + (wn * 64 + fr) * 128 + slot0;

  const int nt = g.K >> 6;
  for (int tt = 0; tt < nt; ++tt) {
    const size_t ko = (size_t)tt * 64;
#pragma unroll
    for (int c = 0; c < 4; ++c)
      GLD16(gA + ko + (size_t)(c * 64) * g.lda, lds + c * 8192 + stgO);
#pragma unroll
    for (int c = 0; c < 2; ++c)
      GLD16(gB + ko + (size_t)(c * 64) * g.ldb, lds + 32768 + c * 8192 + stgO);
    __syncthreads();
#pragma unroll
    for (int kk = 0; kk < 2; ++kk) {
      const int kx = kk ? 64 : 0;
      bf16x8 av[4], bv[4];
#pragma unroll
      for (int mf = 0; mf < 4; ++mf)
        av[mf] = *(const bf16x8*)(lds + ((aoff + mf * 2048) ^ kx));
#pragma unroll
      for (int nf = 0; nf < 4; ++nf)
        bv[nf] = *(const bf16x8*)(lds + ((boff + nf * 2048) ^ kx));
      __builtin_amdgcn_s_setprio(1);
#pragma unroll
      for (int mf = 0; mf < 4; ++mf)
#pragma unroll
        for (int nf = 0; nf < 4; ++nf)
          acc[mf][nf] = __builtin_amdgcn_mfma_f32_16x16x32_bf16(
              av[mf], bv[nf], acc[mf][nf], 0, 0, 0);
      __builtin_amdgcn_s_setprio(0);
    }
    __syncthreads();
  }

  const int em = m0 + wm * 64 + (lane >> 4) * 4;
  const int en = n0 + wn * 64 + fr;
  epilogue4(g, acc, em, en, lane);
}

// ------------- gemm128: 256 thr, 4 waves (2x2 of 64x64) --------------------
__global__ __launch_bounds__(256, 3) void gemm128(GArgs g0, GArgs g1,
                                                  int split) {
  __shared__ char lds[128 * 128 + 16384];

  const bool r1 = (int)blockIdx.x >= split;
  const GArgs g = r1 ? g1 : g0;
  const int lid = blockIdx.x - (r1 ? split : 0);

  const int cpx = g.nwg >> 3;
  const int rid = (lid & 7) * cpx + (lid >> 3);
  const int bx = rid % g.nx, by = rid / g.nx;
  const int m0 = by * 128, n0 = bx * 128;

  const int t = threadIdx.x;
  const int wid = t >> 6, lane = t & 63;
  const int srow = t >> 3;
  const int schunk = ((t & 7) ^ (srow & 7)) * 8;
  const unsigned short* gA = g.A + (size_t)(m0 + srow) * g.lda + schunk;
  const unsigned short* gB =
      g.B + (g.btshift ? (size_t)(m0 >> g.btshift) * g.sBb : 0) +
      (size_t)(n0 + srow) * g.ldb + schunk;
  const int stgO = wid << 10;

  f32x4 acc[4][4] = {};
  const int wm = wid >> 1, wn = wid & 1;
  const int fr = lane & 15;
  const int slot0 = (((lane >> 4) ^ (fr & 7)) << 4);
  const int aoff = (wm * 64 + fr) * 128 + slot0;
  const int boff = 16384 + (wn * 64 + fr) * 128 + slot0;

  const int nt = g.K >> 6;
  for (int tt = 0; tt < nt; ++tt) {
    const size_t ko = (size_t)tt * 64;
#pragma unroll
    for (int c = 0; c < 4; ++c)
      GLD16(gA + ko + (size_t)(c * 32) * g.lda, lds + c * 4096 + stgO);
#pragma unroll
    for (int c = 0; c < 4; ++c)
      GLD16(gB + ko + (size_t)(c * 32) * g.ldb, lds + 16384 + c * 4096 + stgO);
    __syncthreads();
#pragma unroll
    for (int kk = 0; kk < 2; ++kk) {
      const int kx = kk ? 64 : 0;
      bf16x8 av[4], bv[4];
#pragma unroll
      for (int mf = 0; mf < 4; ++mf)
        av[mf] = *(const bf16x8*)(lds + ((aoff + mf * 2048) ^ kx));
#pragma unroll
      for (int nf = 0; nf < 4; ++nf)
        bv[nf] = *(const bf16x8*)(lds + ((boff + nf * 2048) ^ kx));
      __builtin_amdgcn_s_setprio(1);
#pragma unroll
      for (int mf = 0; mf < 4; ++mf)
#pragma unroll
        for (int nf = 0; nf < 4; ++nf)
          acc[mf][nf] = __builtin_amdgcn_mfma_f32_16x16x32_bf16(
              av[mf], bv[nf], acc[mf][nf], 0, 0, 0);
      __builtin_amdgcn_s_setprio(0);
    }
    __syncthreads();
  }

  const int em = m0 + wm * 64 + (lane >> 4) * 4;
  const int en = n0 + wn * 64 + fr;
  epilogue4(g, acc, em, en, lane);
}

// ---------------------------------------------------------------------------
extern "C" void kernel_launch(void* const* d_in, const int* in_sizes, int n_in,
                              void* d_out, int out_size, void* d_ws,
                              size_t ws_size, hipStream_t stream) {
  const float* x   = (const float*)d_in[0];
  const float* gsc = (const float*)d_in[1];
  const float* gbi = (const float*)d_in[2];
  const float* wq  = (const float*)d_in[3];
  const float* bq  = (const float*)d_in[4];
  const float* wk  = (const float*)d_in[5];
  const float* wv  = (const float*)d_in[7];
  const float* bv  = (const float*)d_in[8];
  const float* wp  = (const float*)d_in[9];
  const float* bp  = (const float*)d_in[10];
  float* out = (float*)d_out;

  char* ws = (char*)d_ws;
  const size_t MB = 1024ull * 1024ull;
  unsigned short* hT   = (unsigned short*)(ws);             // 16MB [16384][512]
  unsigned short* tmpB = (unsigned short*)(ws + 16 * MB);   // 16MB [16384][512]
  unsigned short* E    = (unsigned short*)(ws + 48 * MB);   // 32MB [16384][1024]
  unsigned short* vP   = (unsigned short*)(ws + 80 * MB);   // 16MB [16][512][1024]
  unsigned short* WqkT = (unsigned short*)(ws + 96 * MB);   // 0.5MB [512][512]
  unsigned short* W2   = (unsigned short*)(ws + 98 * MB);   // 0.5MB [512][512]
  float*          cu   = (float*)(ws + 99 * MB);            // 2KB
  float*          bpv  = (float*)(ws + 99 * MB + 8 * 1024); // 2KB
  float*          rowsum = (float*)(ws + 99 * MB + 16 * 1024);  // 64KB

  const float rsK = 0.04419417382415922f;  // 512^-0.5

  prep_kernel<<<768, 1024, 0, stream>>>(x, gsc, gbi, hT, wq, wk, wv, wp,
                                        bq, bv, WqkT, W2, cu, bpv, rowsum,
                                        rsK);

  // tmp[m][n] = sum_c hT[m][c] WqkT[n][c] + cu[n]   (rsK pre-folded)
  GArgs tg{hT, WqkT, tmpB, cu, nullptr, nullptr, 0, 0,
           512, 512, 512, 0, 1, 0, 512, 2, 4, 256, 0, 1.f};
  // vP[b][co][j] = sum_c W2[co][c] hT[(b,j)][c] + bpv[co]  (csplit writes)
  GArgs vp{W2, hT, vP, bpv, nullptr, nullptr, 0, 524288,
           512, 512, 1024, 0, 1, 1, 512, 1, 128, 256, 0, 1.f};
  // scores: E[m][j] = exp(tmp_m . hT_{b,j}); rowsum atomic. b = m>>10.
  GArgs sc{tmpB, hT, E, nullptr, nullptr, rowsum, 524288, 0,
           512, 512, 1024, 10, 1, 0, 512, 0, 8, 512, 2, 1.f};
  // PV': out[(b,c)][i] = x + bp[c] + (sum_j vP[(b,c)][j] E[b][i][j])/rowsum
  GArgs pv{vP, E, out, bp, x, rowsum, 1048576, 0,
           1024, 1024, 1024, 9, 0, 0, 1024, 0, 8, 512, 4, 1.f};

  gemm512<<<512, 512, 0, stream>>>(tg, vp, 256);  // tmp || vP, 1 round
  gemm512<<<512, 512, 0, stream>>>(sc, sc, 512);
  gemm128<<<512, 256, 0, stream>>>(pv, pv, 512);
}

// Round 22
// 142.013 us; speedup vs baseline: 1.0212x; 1.0212x over previous
//
#include <hip/hip_runtime.h>
#include <cstdint>
#include <cstddef>

// ---------------------------------------------------------------------------
// AttnBlock, 4 dispatches, every GEMM grid = exactly one resident round:
//   prep(512thr): W2=wp.wv + bpv + rowsum=0; WqkT=rsK*wk^T.wq + cu;
//                 GN true single-pass -> hT
//   tmp|vP: gemm512 (256+256 blocks)   tmp = hT.WqkT^T + cu ; vP = W2.hT + bpv
//   scores: gemm512 (512 blocks)       E = exp(tmp.hT^T) + atomic rowsum
//   PV':    gemm128  (512 blocks)      out = x + bp + vP.E^T / rowsum
// gemm512 = BM256xBN128, 512 thr = 8 waves (4m x 2n), per-wave 64x64,
// 48KB LDS -> 2 blocks/CU = 16 waves/CU (R20: the decisive TLP win).
// Algebra: qk eliminated via softmax shift-invariance (WqkT = rsK*wk^T.wq,
// j-only cu = rsK*wk^T.bq); v/proj folded into W2 = wp.wv.
// Pinned: BM256 4-wave (256,3) spills (R10); grids = 1 round (R12);
// wave-uniform K-loop reads -> LDS-stage (R13); 8-phase loses at K=512 (R16);
// flash fusion blocked at head-dim 512; 1024-thr prep neutral (R21).
// ---------------------------------------------------------------------------

typedef __bf16 bf16x8 __attribute__((ext_vector_type(8)));
typedef float f32x4 __attribute__((ext_vector_type(4)));

typedef __attribute__((address_space(1))) const void gl_void;
typedef __attribute__((address_space(3))) void lds_void;

#define GLD16(g, l)                                                     \
  __builtin_amdgcn_global_load_lds((gl_void*)(uintptr_t)(g),            \
                                   (lds_void*)(uintptr_t)(l), 16, 0, 0)

__device__ __forceinline__ unsigned short f2bf(float f) {
  unsigned int u = __builtin_bit_cast(unsigned int, f);
  u += 0x7fffu + ((u >> 16) & 1u);  // round-to-nearest-even
  return (unsigned short)(u >> 16);
}
__device__ __forceinline__ float bf2f(unsigned int h) {
  return __builtin_bit_cast(float, h << 16);
}

// ---- prep (512 thr): W2 (0-127) + WqkT/cu (128-255) + GN 1-pass (256-767) -
__global__ __launch_bounds__(512) void prep_kernel(
    const float* __restrict__ x, const float* __restrict__ gsc,
    const float* __restrict__ gbi, unsigned short* __restrict__ hT,
    const float* __restrict__ wq, const float* __restrict__ wk,
    const float* __restrict__ wv, const float* __restrict__ wp,
    const float* __restrict__ bq, const float* __restrict__ bv,
    unsigned short* __restrict__ WqkTo, unsigned short* __restrict__ W2o,
    float* __restrict__ cu, float* __restrict__ bpv,
    float* __restrict__ rowsum, float rsK) {
  const int t = threadIdx.x;
  const int wid = t >> 6, lane = t & 63;
  if (blockIdx.x < 128) {  // ---- W2 = wp.wv (fp32), bpv = wp.bv, rowsum=0 ----
    __shared__ float swp[4][512];
    __shared__ float sbv[512];
    __shared__ float redp[4][8];
    const int o0 = blockIdx.x * 4;
#pragma unroll
    for (int r = 0; r < 4; ++r)
      swp[r][t] = wp[(size_t)(o0 + r) * 512 + t];
    sbv[t] = bv[t];
    if (t < 128) rowsum[blockIdx.x * 128 + t] = 0.f;
    __syncthreads();
    float a0[4] = {};
    for (int c = 0; c < 512; ++c) {
      const float v0 = wv[(size_t)c * 512 + t];
#pragma unroll
      for (int r = 0; r < 4; ++r) a0[r] = fmaf(swp[r][c], v0, a0[r]);
    }
#pragma unroll
    for (int r = 0; r < 4; ++r)
      W2o[(size_t)(o0 + r) * 512 + t] = f2bf(a0[r]);
    float s[4];
#pragma unroll
    for (int r = 0; r < 4; ++r) s[r] = swp[r][t] * sbv[t];
#pragma unroll
    for (int r = 0; r < 4; ++r)
#pragma unroll
      for (int off = 32; off > 0; off >>= 1) s[r] += __shfl_down(s[r], off);
    if (lane == 0) {
#pragma unroll
      for (int r = 0; r < 4; ++r) redp[r][wid] = s[r];
    }
    __syncthreads();
    if (t == 0) {
#pragma unroll
      for (int r = 0; r < 4; ++r) {
        float acc = 0.f;
#pragma unroll
        for (int w = 0; w < 8; ++w) acc += redp[r][w];
        bpv[o0 + r] = acc;
      }
    }
    return;
  }
  if (blockIdx.x < 256) {  // ---- WqkT[n][c] = rsK*sum_o wk[o][n] wq[o][c] ----
    __shared__ float swk[512][4];
    __shared__ float sbq[512];
    __shared__ float redq[4][8];
    const int n0 = (blockIdx.x - 128) * 4;
    *(float4*)&swk[t][0] = *(const float4*)&wk[(size_t)t * 512 + n0];
    sbq[t] = bq[t];
    __syncthreads();
    float a0[4] = {};
    for (int o = 0; o < 512; ++o) {
      const float q0 = wq[(size_t)o * 512 + t];
#pragma unroll
      for (int r = 0; r < 4; ++r) a0[r] = fmaf(swk[o][r], q0, a0[r]);
    }
#pragma unroll
    for (int r = 0; r < 4; ++r)
      WqkTo[(size_t)(n0 + r) * 512 + t] = f2bf(a0[r] * rsK);
    float s[4];
#pragma unroll
    for (int r = 0; r < 4; ++r) s[r] = swk[t][r] * sbq[t];
#pragma unroll
    for (int r = 0; r < 4; ++r)
#pragma unroll
      for (int off = 32; off > 0; off >>= 1) s[r] += __shfl_down(s[r], off);
    if (lane == 0) {
#pragma unroll
      for (int r = 0; r < 4; ++r) redq[r][wid] = s[r];
    }
    __syncthreads();
    if (t == 0) {
#pragma unroll
      for (int r = 0; r < 4; ++r) {
        float acc = 0.f;
#pragma unroll
        for (int w = 0; w < 8; ++w) acc += redq[r][w];
        cu[n0 + r] = rsK * acc;
      }
    }
    return;
  }
  // ---- GroupNorm, single pass: thread (col, chalf) owns 8 chans ----
  __shared__ float red[2][8];
  const int gb = blockIdx.x - 256;
  const int b = gb >> 5;
  const int g = gb & 31;
  const int col = t & 255;
  const int chalf = t >> 8;
  const float* xp = x + ((size_t)(b * 512 + g * 16 + chalf * 8)) * 1024;

  float4 r4[8];
  float s = 0.f, s2 = 0.f;
#pragma unroll
  for (int c = 0; c < 8; ++c) {
    r4[c] = ((const float4*)(xp + (size_t)c * 1024))[col];
    s += (r4[c].x + r4[c].y) + (r4[c].z + r4[c].w);
    s2 += (r4[c].x * r4[c].x + r4[c].y * r4[c].y) +
          (r4[c].z * r4[c].z + r4[c].w * r4[c].w);
  }
#pragma unroll
  for (int off = 32; off > 0; off >>= 1) {
    s += __shfl_down(s, off);
    s2 += __shfl_down(s2, off);
  }
  if (lane == 0) { red[0][wid] = s; red[1][wid] = s2; }
  __syncthreads();
  float S = 0.f, S2 = 0.f;
#pragma unroll
  for (int w = 0; w < 8; ++w) { S += red[0][w]; S2 += red[1][w]; }
  const float mean = S * (1.f / 16384.f);
  const float var = S2 * (1.f / 16384.f) - mean * mean;
  const float rstd = rsqrtf(var + 1e-6f);

  float sc[8], bi[8];
#pragma unroll
  for (int c = 0; c < 8; ++c) {
    sc[c] = gsc[g * 16 + chalf * 8 + c] * rstd;
    bi[c] = gbi[g * 16 + chalf * 8 + c] - mean * sc[c];
  }
  unsigned short* hp = hT + (size_t)b * 1024 * 512 + g * 16 + chalf * 8;
#pragma unroll
  for (int ii = 0; ii < 4; ++ii) {
    const int i = 4 * col + ii;
    unsigned int pk[4];
#pragma unroll
    for (int p = 0; p < 4; ++p) {
      float e0, e1;
      if (ii == 0) { e0 = r4[2 * p].x; e1 = r4[2 * p + 1].x; }
      else if (ii == 1) { e0 = r4[2 * p].y; e1 = r4[2 * p + 1].y; }
      else if (ii == 2) { e0 = r4[2 * p].z; e1 = r4[2 * p + 1].z; }
      else { e0 = r4[2 * p].w; e1 = r4[2 * p + 1].w; }
      const float v0 = e0 * sc[2 * p] + bi[2 * p];
      const float v1 = e1 * sc[2 * p + 1] + bi[2 * p + 1];
      pk[p] = (unsigned int)f2bf(v0) | ((unsigned int)f2bf(v1) << 16);
    }
    *(uint4*)(hp + (size_t)i * 512) = make_uint4(pk[0], pk[1], pk[2], pk[3]);
  }
}

// ------------------------- GEMM argument block -----------------------------
struct GArgs {
  const unsigned short *A, *B;
  void* Out;
  const float *bias, *resid;
  float* rowsum;
  long long sBb, sOb;
  int lda, ldb, ldo, btshift, obf, csplit, K, bmode, nx, nwg, epi;
  float scale;
};

// Shared epilogue (per-wave 64x64 tile, MF=4), used by both engines.
__device__ __forceinline__ void epilogue4(
    const GArgs& g, f32x4 acc[4][4], int em, int en, int lane) {
  float rdiv[4];
  if (g.epi == 4) {
    const int rbase = ((em >> 9) << 10);  // batch = row>>9
#pragma unroll
    for (int nf = 0; nf < 4; ++nf)
      rdiv[nf] = 1.f / g.rowsum[rbase + en + nf * 16];
  }
#pragma unroll
  for (int mf = 0; mf < 4; ++mf) {
#pragma unroll
    for (int r = 0; r < 4; ++r) {
      const int gm = em + mf * 16 + r;
      if (g.epi == 2) {  // scores: exp, atomic row sum of ROUNDED values
        float rsum = 0.f;
#pragma unroll
        for (int nf = 0; nf < 4; ++nf) {
          const int gn = en + nf * 16;
          unsigned short h = f2bf(__expf(acc[mf][nf][r] * g.scale));
          rsum += bf2f(h);
          ((unsigned short*)g.Out)[(size_t)gm * g.ldo + gn] = h;
        }
        rsum += __shfl_xor(rsum, 1);
        rsum += __shfl_xor(rsum, 2);
        rsum += __shfl_xor(rsum, 4);
        rsum += __shfl_xor(rsum, 8);
        if ((lane & 15) == 0) atomicAdd(&g.rowsum[gm], rsum);
        continue;
      }
      if (g.epi == 4) {  // PV': normalize + bias + resid, fp32 row-major
        const float bb = g.bias[gm & 511];
#pragma unroll
        for (int nf = 0; nf < 4; ++nf) {
          const int gn = en + nf * 16;
          const size_t off = (size_t)gm * g.ldo + gn;
          ((float*)g.Out)[off] = acc[mf][nf][r] * rdiv[nf] + bb + g.resid[off];
        }
        continue;
      }
#pragma unroll
      for (int nf = 0; nf < 4; ++nf) {
        const int gn = en + nf * 16;
        float v = acc[mf][nf][r] * g.scale;
        if (g.bmode == 1) v += g.bias[gm];
        else if (g.bmode == 2) v += g.bias[gn];
        size_t off;
        if (g.csplit)
          off = (size_t)(gn >> 10) * g.sOb + (size_t)gm * g.ldo + (gn & 1023);
        else
          off = (size_t)gm * g.ldo + gn;
        if (g.resid) v += g.resid[off];
        if (g.obf) ((unsigned short*)g.Out)[off] = f2bf(v);
        else ((float*)g.Out)[off] = v;
      }
    }
  }
}

// -------- gemm512: BM256 x BN128, 512 thr = 8 waves (4m x 2n) --------------
__global__ __launch_bounds__(512) void gemm512(GArgs g0, GArgs g1, int split) {
  __shared__ char lds[49152];  // A 32KB @0, B 16KB @32768

  const bool r1 = (int)blockIdx.x >= split;
  const GArgs g = r1 ? g1 : g0;
  const int lid = blockIdx.x - (r1 ? split : 0);

  const int cpx = g.nwg >> 3;
  const int rid = (lid & 7) * cpx + (lid >> 3);
  const int bx = rid % g.nx, by = rid / g.nx;
  const int m0 = by * 256, n0 = bx * 128;

  const int t = threadIdx.x;  // 0..511
  const int wid = t >> 6, lane = t & 63;
  const int srow = t >> 3;
  const int schunk = ((t & 7) ^ (srow & 7)) * 8;
  const unsigned short* gA = g.A + (size_t)(m0 + srow) * g.lda + schunk;
  const unsigned short* gB =
      g.B + (g.btshift ? (size_t)(m0 >> g.btshift) * g.sBb : 0) +
      (size_t)(n0 + srow) * g.ldb + schunk;
  const int stgO = wid << 10;

  f32x4 acc[4][4] = {};
  const int wm = wid >> 1, wn = wid & 1;
  const int fr = lane & 15;
  const int slot0 = (((lane >> 4) ^ (fr & 7)) << 4);
  const int aoff = (wm * 64 + fr) * 128 + slot0;
  const int boff = 32768 + (wn * 64 + fr) * 128 + slot0;

  const int nt = g.K >> 6;
  for (int tt = 0; tt < nt; ++tt) {
    const size_t ko = (size_t)tt * 64;
#pragma unroll
    for (int c = 0; c < 4; ++c)
      GLD16(gA + ko + (size_t)(c * 64) * g.lda, lds + c * 8192 + stgO);
#pragma unroll
    for (int c = 0; c < 2; ++c)
      GLD16(gB + ko + (size_t)(c * 64) * g.ldb, lds + 32768 + c * 8192 + stgO);
    __syncthreads();
#pragma unroll
    for (int kk = 0; kk < 2; ++kk) {
      const int kx = kk ? 64 : 0;
      bf16x8 av[4], bv[4];
#pragma unroll
      for (int mf = 0; mf < 4; ++mf)
        av[mf] = *(const bf16x8*)(lds + ((aoff + mf * 2048) ^ kx));
#pragma unroll
      for (int nf = 0; nf < 4; ++nf)
        bv[nf] = *(const bf16x8*)(lds + ((boff + nf * 2048) ^ kx));
      __builtin_amdgcn_s_setprio(1);
#pragma unroll
      for (int mf = 0; mf < 4; ++mf)
#pragma unroll
        for (int nf = 0; nf < 4; ++nf)
          acc[mf][nf] = __builtin_amdgcn_mfma_f32_16x16x32_bf16(
              av[mf], bv[nf], acc[mf][nf], 0, 0, 0);
      __builtin_amdgcn_s_setprio(0);
    }
    __syncthreads();
  }

  const int em = m0 + wm * 64 + (lane >> 4) * 4;
  const int en = n0 + wn * 64 + fr;
  epilogue4(g, acc, em, en, lane);
}

// ------------- gemm128: 256 thr, 4 waves (2x2 of 64x64) --------------------
__global__ __launch_bounds__(256, 3) void gemm128(GArgs g0, GArgs g1,
                                                  int split) {
  __shared__ char lds[128 * 128 + 16384];

  const bool r1 = (int)blockIdx.x >= split;
  const GArgs g = r1 ? g1 : g0;
  const int lid = blockIdx.x - (r1 ? split : 0);

  const int cpx = g.nwg >> 3;
  const int rid = (lid & 7) * cpx + (lid >> 3);
  const int bx = rid % g.nx, by = rid / g.nx;
  const int m0 = by * 128, n0 = bx * 128;

  const int t = threadIdx.x;
  const int wid = t >> 6, lane = t & 63;
  const int srow = t >> 3;
  const int schunk = ((t & 7) ^ (srow & 7)) * 8;
  const unsigned short* gA = g.A + (size_t)(m0 + srow) * g.lda + schunk;
  const unsigned short* gB =
      g.B + (g.btshift ? (size_t)(m0 >> g.btshift) * g.sBb : 0) +
      (size_t)(n0 + srow) * g.ldb + schunk;
  const int stgO = wid << 10;

  f32x4 acc[4][4] = {};
  const int wm = wid >> 1, wn = wid & 1;
  const int fr = lane & 15;
  const int slot0 = (((lane >> 4) ^ (fr & 7)) << 4);
  const int aoff = (wm * 64 + fr) * 128 + slot0;
  const int boff = 16384 + (wn * 64 + fr) * 128 + slot0;

  const int nt = g.K >> 6;
  for (int tt = 0; tt < nt; ++tt) {
    const size_t ko = (size_t)tt * 64;
#pragma unroll
    for (int c = 0; c < 4; ++c)
      GLD16(gA + ko + (size_t)(c * 32) * g.lda, lds + c * 4096 + stgO);
#pragma unroll
    for (int c = 0; c < 4; ++c)
      GLD16(gB + ko + (size_t)(c * 32) * g.ldb, lds + 16384 + c * 4096 + stgO);
    __syncthreads();
#pragma unroll
    for (int kk = 0; kk < 2; ++kk) {
      const int kx = kk ? 64 : 0;
      bf16x8 av[4], bv[4];
#pragma unroll
      for (int mf = 0; mf < 4; ++mf)
        av[mf] = *(const bf16x8*)(lds + ((aoff + mf * 2048) ^ kx));
#pragma unroll
      for (int nf = 0; nf < 4; ++nf)
        bv[nf] = *(const bf16x8*)(lds + ((boff + nf * 2048) ^ kx));
      __builtin_amdgcn_s_setprio(1);
#pragma unroll
      for (int mf = 0; mf < 4; ++mf)
#pragma unroll
        for (int nf = 0; nf < 4; ++nf)
          acc[mf][nf] = __builtin_amdgcn_mfma_f32_16x16x32_bf16(
              av[mf], bv[nf], acc[mf][nf], 0, 0, 0);
      __builtin_amdgcn_s_setprio(0);
    }
    __syncthreads();
  }

  const int em = m0 + wm * 64 + (lane >> 4) * 4;
  const int en = n0 + wn * 64 + fr;
  epilogue4(g, acc, em, en, lane);
}

// ---------------------------------------------------------------------------
extern "C" void kernel_launch(void* const* d_in, const int* in_sizes, int n_in,
                              void* d_out, int out_size, void* d_ws,
                              size_t ws_size, hipStream_t stream) {
  const float* x   = (const float*)d_in[0];
  const float* gsc = (const float*)d_in[1];
  const float* gbi = (const float*)d_in[2];
  const float* wq  = (const float*)d_in[3];
  const float* bq  = (const float*)d_in[4];
  const float* wk  = (const float*)d_in[5];
  const float* wv  = (const float*)d_in[7];
  const float* bv  = (const float*)d_in[8];
  const float* wp  = (const float*)d_in[9];
  const float* bp  = (const float*)d_in[10];
  float* out = (float*)d_out;

  char* ws = (char*)d_ws;
  const size_t MB = 1024ull * 1024ull;
  unsigned short* hT   = (unsigned short*)(ws);             // 16MB [16384][512]
  unsigned short* tmpB = (unsigned short*)(ws + 16 * MB);   // 16MB [16384][512]
  unsigned short* E    = (unsigned short*)(ws + 48 * MB);   // 32MB [16384][1024]
  unsigned short* vP   = (unsigned short*)(ws + 80 * MB);   // 16MB [16][512][1024]
  unsigned short* WqkT = (unsigned short*)(ws + 96 * MB);   // 0.5MB [512][512]
  unsigned short* W2   = (unsigned short*)(ws + 98 * MB);   // 0.5MB [512][512]
  float*          cu   = (float*)(ws + 99 * MB);            // 2KB
  float*          bpv  = (float*)(ws + 99 * MB + 8 * 1024); // 2KB
  float*          rowsum = (float*)(ws + 99 * MB + 16 * 1024);  // 64KB

  const float rsK = 0.04419417382415922f;  // 512^-0.5

  prep_kernel<<<768, 512, 0, stream>>>(x, gsc, gbi, hT, wq, wk, wv, wp,
                                       bq, bv, WqkT, W2, cu, bpv, rowsum,
                                       rsK);

  // tmp[m][n] = sum_c hT[m][c] WqkT[n][c] + cu[n]   (rsK pre-folded)
  GArgs tg{hT, WqkT, tmpB, cu, nullptr, nullptr, 0, 0,
           512, 512, 512, 0, 1, 0, 512, 2, 4, 256, 0, 1.f};
  // vP[b][co][j] = sum_c W2[co][c] hT[(b,j)][c] + bpv[co]  (csplit writes)
  GArgs vp{W2, hT, vP, bpv, nullptr, nullptr, 0, 524288,
           512, 512, 1024, 0, 1, 1, 512, 1, 128, 256, 0, 1.f};
  // scores: E[m][j] = exp(tmp_m . hT_{b,j}); rowsum atomic. b = m>>10.
  GArgs sc{tmpB, hT, E, nullptr, nullptr, rowsum, 524288, 0,
           512, 512, 1024, 10, 1, 0, 512, 0, 8, 512, 2, 1.f};
  // PV': out[(b,c)][i] = x + bp[c] + (sum_j vP[(b,c)][j] E[b][i][j])/rowsum
  GArgs pv{vP, E, out, bp, x, rowsum, 1048576, 0,
           1024, 1024, 1024, 9, 0, 0, 1024, 0, 8, 512, 4, 1.f};

  gemm512<<<512, 512, 0, stream>>>(tg, vp, 256);  // tmp || vP, 1 round
  gemm512<<<512, 512, 0, stream>>>(sc, sc, 512);
  gemm128<<<512, 256, 0, stream>>>(pv, pv, 512);
}